// Round 1
// baseline (1656.402 us; speedup 1.0000x reference)
//
#include <hip/hip_runtime.h>
#include <hip/hip_bf16.h>
#include <stdint.h>

// MultilayerPCN: bf16-MFMA, 256x64 full-M tiles, full-K per block, barrier-free K-loop.
// NODES = [2048, 4096, 8192], B = 256, n_iters = 8 (hardcoded), LAMB = 0.5.
//
// Block = 512 thr = 8 waves = 4 rowBlks x 2 K-halves; each wave computes a 64x64
// C-tile from its K/2 slice (4x4 mfma_f32_16x16x32_bf16 frags, 64 fp32 acc).
// Weight matrix B is read ONCE per GEMM (was 4x with 64-row tiles): phase traffic
// 640 MB -> 400 MB at the ~7.4 TB/s L2-miss wall. B-slice request redundancy
// (4 same-K-half waves) is absorbed by L1/L2 within the CU.
// Staging: per-wave private double-buffered LDS (2 x 8KB per wave, 128KB/block)
// via global_load_lds width-16. No __syncthreads in the K-loop: per-wave
// s_waitcnt vmcnt(8) (prefetch depth 1, never drains to 0) with sched_barrier(0)
// fences. K-half partials pair-reduced in LDS (reusing staging), then fused
// 512-thread epilogue over the 4 row-block tiles (node update / tanh / errs / loss).
//
// Per iteration, 2 launches:
//   phase1: [G2 = e2@W1 || G1 = e1@W0]      96 blocks (64 + 32)
//   phase2: [G4 = T1@W1^T || G3 = T0@W0^T] 192 blocks (128 + 64)

typedef short short8x __attribute__((ext_vector_type(8)));
typedef float float4x __attribute__((ext_vector_type(4)));
typedef unsigned short u16;
typedef u16 u16x8 __attribute__((ext_vector_type(8)));

static constexpr float LOSS_SCALE = 100.0f / 256.0f;

__device__ __forceinline__ u16 f2b(float x) {
    union { float f; uint32_t u; } v{x};
    uint32_t b = v.u + 0x7fffu + ((v.u >> 16) & 1u);
    return (u16)(b >> 16);
}

__device__ __forceinline__ float signf_(float x) {
    return (x > 0.f) ? 1.f : ((x < 0.f) ? -1.f : 0.f);
}

__device__ __forceinline__ void gload_lds16(const void* g, void* lds) {
    __builtin_amdgcn_global_load_lds(
        (const __attribute__((address_space(1))) void*)g,
        (__attribute__((address_space(3))) void*)lds, 16, 0, 0);
}

// ---------------- init / cast kernels ----------------
__global__ void k_zero(float* p, int n) {
    int i = blockIdx.x * blockDim.x + threadIdx.x;
    if (i < n) p[i] = 0.f;
}

// one pass: outN = bf16(in) (R x C), outT = bf16(in^T) (C x R)
__global__ __launch_bounds__(256) void k_cast_both(
    const float* __restrict__ in, u16* __restrict__ outN, u16* __restrict__ outT,
    int R, int C) {
    __shared__ float tile[32][33];
    int x = blockIdx.x * 32 + threadIdx.x;
#pragma unroll
    for (int k = 0; k < 32; k += 8) {
        int y = blockIdx.y * 32 + threadIdx.y + k;
        float v = in[(size_t)y * C + x];
        tile[threadIdx.y + k][threadIdx.x] = v;
        outN[(size_t)y * C + x] = f2b(v);
    }
    __syncthreads();
    int ox = blockIdx.y * 32 + threadIdx.x;
#pragma unroll
    for (int k = 0; k < 32; k += 8) {
        int oy = blockIdx.x * 32 + threadIdx.y + k;
        outT[(size_t)oy * R + ox] = f2b(tile[threadIdx.x][threadIdx.y + k]);
    }
}

__global__ void k_fill_v0(float* __restrict__ v0, const float* __restrict__ memory,
                          int n, int mask) {
    int i = blockIdx.x * blockDim.x + threadIdx.x;
    if (i < n) v0[i] = memory[i & mask];
}

__global__ void k_tanh(float* __restrict__ dst, const float* __restrict__ src, int n) {
    int i = blockIdx.x * blockDim.x + threadIdx.x;
    if (i < n) dst[i] = tanhf(src[i]);
}

__global__ void k_rowdot(const float* __restrict__ x, const float* __restrict__ W,
                         float* __restrict__ out, int K) {
    int i = blockIdx.x;
    const float* w = W + (size_t)i * K;
    float s = 0.f;
    for (int j = threadIdx.x; j < K; j += 256) s += x[j] * w[j];
    __shared__ float red[256];
    red[threadIdx.x] = s;
    __syncthreads();
    for (int st = 128; st > 0; st >>= 1) {
        if (threadIdx.x < st) red[threadIdx.x] += red[threadIdx.x + st];
        __syncthreads();
    }
    if (threadIdx.x == 0) out[i] = red[0];
}

__global__ void k_bcast_v1_e1(float* __restrict__ v1, float* __restrict__ e1,
                              u16* __restrict__ e1b,
                              const float* __restrict__ r1, int n, int mask) {
    int i = blockIdx.x * blockDim.x + threadIdx.x;
    if (i < n) { v1[i] = r1[i & mask]; e1[i] = 0.f; e1b[i] = 0; }
}

__global__ void k_e2_init(u16* __restrict__ e2b, const float* __restrict__ inp,
                          const float* __restrict__ r2, int n, int mask) {
    int i = blockIdx.x * blockDim.x + threadIdx.x;
    if (i < n) e2b[i] = f2b(inp[i] - r2[i & mask]);
}

// ---------------- full-M (256x64) full-K MFMA GEMM ----------------
struct GDR {
    const u16* A;       // [256, K] bf16 row-major
    const u16* Bt;      // [N, K]  bf16 row-major (B transposed)
    const float* x0;    // epilogue input 0
    const float* x1;    // epilogue input 1
    float* y0;          // fp32 state output
    u16* y0b;           // bf16 copy of y0 (EPI3)
    u16* y1b;           // bf16 aux output (T0b/T1b/e2b)
    float* loss;        // loss accumulator (EPI != 2)
    const float* lr;    // inf_lr (EPI1/2)
    int N, K, nCol;     // nCol = N/64 = tiles (blocks) for this GEMM
};

template <int EPI>
__device__ void gemm_tile(const GDR& g, int tile, u16* stage, float* red8) {
    const int t = threadIdx.x;
    const int w = t >> 6, l = t & 63;
    const int lm = l & 15, lq = l >> 4;
    const int col0 = tile * 64;           // full-M block: tile index = colBlk
    const int K = g.K;
    const int rb_ = w >> 1, kh = w & 1;   // rowBlk (0..3), K-half (0..1)
    const int Ksl = K >> 1;               // this wave's K-slice length
    const int nCh = Ksl >> 5;             // chunks of 32 (min 32)

    // per-wave private staging: 16KB region; buf b: A at b*4096 u16, B at +2048
    u16* base = stage + (w << 13);
    const u16* aSrc = g.A + (size_t)(rb_ * 64 + (l >> 2)) * K + kh * Ksl + (l & 3) * 8;
    const u16* bSrc = g.Bt + (size_t)(col0 + (l >> 2)) * K + kh * Ksl + (l & 3) * 8;
    const size_t rStep = (size_t)16 * K;   // 16 rows per staging issue

    int aoff[4], boff[4];
#pragma unroll
    for (int i = 0; i < 4; ++i) { aoff[i] = (i * 16 + lm) * 32 + lq * 8; boff[i] = aoff[i]; }

    float4x acc[4][4];
#pragma unroll
    for (int i = 0; i < 4; ++i)
#pragma unroll
        for (int j = 0; j < 4; ++j) acc[i][j] = (float4x)0.f;

#define ISSUE(c, b) { \
    u16* ab = base + (b) * 4096; \
    const u16* as = aSrc + (c) * 32; \
    const u16* bs = bSrc + (c) * 32; \
    gload_lds16(as, ab);             gload_lds16(as + rStep, ab + 512); \
    gload_lds16(as + 2*rStep, ab + 1024); gload_lds16(as + 3*rStep, ab + 1536); \
    gload_lds16(bs, ab + 2048);      gload_lds16(bs + rStep, ab + 2560); \
    gload_lds16(bs + 2*rStep, ab + 3072); gload_lds16(bs + 3*rStep, ab + 3584); }

#define COMPUTE(b) { \
    u16* ab = base + (b) * 4096; \
    short8x a[4], bb[4]; \
    _Pragma("unroll") for (int i = 0; i < 4; ++i) a[i] = *(const short8x*)(ab + aoff[i]); \
    _Pragma("unroll") for (int j = 0; j < 4; ++j) bb[j] = *(const short8x*)(ab + 2048 + boff[j]); \
    _Pragma("unroll") for (int i = 0; i < 4; ++i) \
    _Pragma("unroll") for (int j = 0; j < 4; ++j) \
        acc[i][j] = __builtin_amdgcn_mfma_f32_16x16x32_bf16(a[i], bb[j], acc[i][j], 0, 0, 0); }

    ISSUE(0, 0);
    int c = 0;
    for (; c < nCh - 1; ++c) {
        __builtin_amdgcn_sched_barrier(0);
        ISSUE(c + 1, (c + 1) & 1);
        __builtin_amdgcn_sched_barrier(0);
        __builtin_amdgcn_s_waitcnt(0x0F78);   // vmcnt(8): chunk c staged
        __builtin_amdgcn_sched_barrier(0);
        COMPUTE(c & 1);
    }
    __builtin_amdgcn_sched_barrier(0);
    __builtin_amdgcn_s_waitcnt(0x0F70);       // vmcnt(0): last chunk staged
    __builtin_amdgcn_sched_barrier(0);
    COMPUTE(c & 1);
#undef ISSUE
#undef COMPUTE

    // ---- pair-reduce the 2 K-half partials per rowBlk in LDS (reuse staging) ----
    // rowBlk tile rb_ = fp32 64x64 at stage + rb_*16KB; frag (i,j) reg r maps to
    // row = i*16 + lq*4 + r, col = j*16 + lm  [C/D layout, m89-verified]
    float* T = (float*)stage;
    __syncthreads();                 // all waves done with staging reads
    if (kh) {
        float* tw = T + rb_ * 4096;
#pragma unroll
        for (int i = 0; i < 4; ++i)
#pragma unroll
            for (int j = 0; j < 4; ++j)
#pragma unroll
                for (int r = 0; r < 4; ++r)
                    tw[(i * 16 + lq * 4 + r) * 64 + j * 16 + lm] = acc[i][j][r];
    }
    __syncthreads();
    if (!kh) {
        float* tw = T + rb_ * 4096;
#pragma unroll
        for (int i = 0; i < 4; ++i)
#pragma unroll
            for (int j = 0; j < 4; ++j)
#pragma unroll
                for (int r = 0; r < 4; ++r)
                    tw[(i * 16 + lq * 4 + r) * 64 + j * 16 + lm] += acc[i][j][r];
    }
    __syncthreads();

    // ---- fused epilogue over the 4 row-block tiles:
    //      thread t handles row = t>>3, cols c8..c8+7 of each tile ----
    const int row = t >> 3, c8 = (t & 7) * 8;
    float lr = 0.f;
    if (EPI == 1 || EPI == 2) lr = *g.lr;
    float lsum = 0.f;

#pragma unroll
    for (int rb = 0; rb < 4; ++rb) {
        const float* Tb = T + rb * 4096;
        const size_t idx = (size_t)(rb * 64 + row) * g.N + col0 + c8;
        float4x cv[2];
        cv[0] = *(const float4x*)(Tb + row * 64 + c8);
        cv[1] = *(const float4x*)(Tb + row * 64 + c8 + 4);

        if (EPI == 1) {
            float4x vv[2], mm[2], nv[2]; u16x8 tb;
            vv[0] = *(const float4x*)(g.x0 + idx);       vv[1] = *(const float4x*)(g.x0 + idx + 4);
            mm[0] = *(const float4x*)(g.x1 + col0 + c8); mm[1] = *(const float4x*)(g.x1 + col0 + c8 + 4);
#pragma unroll
            for (int h = 0; h < 2; ++h)
#pragma unroll
                for (int e = 0; e < 4; ++e) {
                    float v = vv[h][e], th = tanhf(v), td = 1.f - th * th;
                    float d0 = (mm[h][e] - v) - 0.5f * signf_(v) + td * cv[h][e];
                    float x = v + lr * d0;
                    x = x > 0.f ? x : 0.f;
                    nv[h][e] = x;
                    tb[h * 4 + e] = f2b(tanhf(x));
                    float ne0 = x - mm[h][e];
                    lsum += ne0 * ne0;
                }
            *(float4x*)(g.y0 + idx) = nv[0];
            *(float4x*)(g.y0 + idx + 4) = nv[1];
            *(u16x8*)(g.y1b + idx) = tb;
        } else if (EPI == 2) {
            float4x vv[2], ee[2], nv[2]; u16x8 tb;
            vv[0] = *(const float4x*)(g.x0 + idx);     vv[1] = *(const float4x*)(g.x0 + idx + 4);
            ee[0] = *(const float4x*)(g.x1 + idx);     ee[1] = *(const float4x*)(g.x1 + idx + 4);
#pragma unroll
            for (int h = 0; h < 2; ++h)
#pragma unroll
                for (int e = 0; e < 4; ++e) {
                    float v = vv[h][e], th = tanhf(v), td = 1.f - th * th;
                    float x = v + lr * (-ee[h][e] + td * cv[h][e]);
                    x = x > 0.f ? x : 0.f;
                    nv[h][e] = x;
                    tb[h * 4 + e] = f2b(tanhf(x));
                }
            *(float4x*)(g.y0 + idx) = nv[0];
            *(float4x*)(g.y0 + idx + 4) = nv[1];
            *(u16x8*)(g.y1b + idx) = tb;
        } else if (EPI == 3) {
            float4x vv[2], ne[2]; u16x8 nb;
            vv[0] = *(const float4x*)(g.x0 + idx);     vv[1] = *(const float4x*)(g.x0 + idx + 4);
#pragma unroll
            for (int h = 0; h < 2; ++h)
#pragma unroll
                for (int e = 0; e < 4; ++e) {
                    float x = vv[h][e] - cv[h][e];
                    ne[h][e] = x;
                    nb[h * 4 + e] = f2b(x);
                    lsum += x * x;
                }
            *(float4x*)(g.y0 + idx) = ne[0];
            *(float4x*)(g.y0 + idx + 4) = ne[1];
            *(u16x8*)(g.y0b + idx) = nb;
        } else {
            float4x vv[2]; u16x8 nb;
            vv[0] = *(const float4x*)(g.x0 + idx);     vv[1] = *(const float4x*)(g.x0 + idx + 4);
#pragma unroll
            for (int h = 0; h < 2; ++h)
#pragma unroll
                for (int e = 0; e < 4; ++e) {
                    float x = vv[h][e] - cv[h][e];
                    nb[h * 4 + e] = f2b(x);
                    lsum += x * x;
                }
            *(u16x8*)(g.y1b + idx) = nb;
        }
    }

    if (EPI != 2) {
#pragma unroll
        for (int off = 32; off > 0; off >>= 1) lsum += __shfl_down(lsum, off);
        if (l == 0) red8[w] = lsum;
        __syncthreads();
        if (t == 0) {
            float s = 0.f;
#pragma unroll
            for (int q = 0; q < 8; ++q) s += red8[q];
            atomicAdd(g.loss, s * LOSS_SCALE);
        }
    }
}

template <int EPIA, int EPIB>
__global__ __launch_bounds__(512, 2) void pcn_pair(GDR ga, GDR gb, int nA) {
    __shared__ u16 stage[65536];   // 128 KB
    __shared__ float red8[8];
    int bx = blockIdx.x;
    if (bx < nA) gemm_tile<EPIA>(ga, bx, stage, red8);
    else         gemm_tile<EPIB>(gb, bx - nA, stage, red8);
}

extern "C" void kernel_launch(void* const* d_in, const int* in_sizes, int n_in,
                              void* d_out, int out_size, void* d_ws, size_t ws_size,
                              hipStream_t stream)
{
    const float* batch_inp = (const float*)d_in[0]; // (256, 8192)
    const float* W0        = (const float*)d_in[1]; // (4096, 2048)
    const float* W1        = (const float*)d_in[2]; // (8192, 4096)
    const float* memory    = (const float*)d_in[3]; // (2048,)
    const float* lr_ptr    = (const float*)d_in[5]; // 0.05
    float* out = (float*)d_out;                     // 8 losses

    const int n0 = 2048, n1 = 4096, n2 = 8192, Bn = 256;

    // ---- workspace layout ----
    char* ws = (char*)d_ws;
    auto alloc_f = [&](size_t n) { float* p = (float*)ws; ws += n * 4; return p; };
    auto alloc_b = [&](size_t n) { u16* p = (u16*)ws; ws += n * 2; return p; };

    float* v0  = alloc_f((size_t)Bn * n0);
    float* v1  = alloc_f((size_t)Bn * n1);
    float* e1  = alloc_f((size_t)Bn * n1);
    u16*   e1b = alloc_b((size_t)Bn * n1);
    u16*   e2b = alloc_b((size_t)Bn * n2);
    u16*   T0b = alloc_b((size_t)Bn * n0);
    u16*   T1b = alloc_b((size_t)Bn * n1);
    u16*   W0b  = alloc_b((size_t)n1 * n0);   // (n1, n0) = W0 cast
    u16*   W0Tb = alloc_b((size_t)n0 * n1);   // (n0, n1) = W0^T cast
    u16*   W1b  = alloc_b((size_t)n2 * n1);   // (n2, n1) = W1 cast
    u16*   W1Tb = alloc_b((size_t)n1 * n2);   // (n1, n2) = W1^T cast
    float* tm = alloc_f(n0);
    float* r1 = alloc_f(n1);
    float* t1 = alloc_f(n1);
    float* r2 = alloc_f(n2);

    // ---- one-time init ----
    k_zero<<<1, 32, 0, stream>>>(out, 8);
    k_cast_both<<<dim3(n0 / 32, n1 / 32), dim3(32, 8), 0, stream>>>(W0, W0b, W0Tb, n1, n0);
    k_cast_both<<<dim3(n1 / 32, n2 / 32), dim3(32, 8), 0, stream>>>(W1, W1b, W1Tb, n2, n1);
    k_fill_v0<<<(Bn * n0) / 256, 256, 0, stream>>>(v0, memory, Bn * n0, n0 - 1);
    k_tanh<<<n0 / 256, 256, 0, stream>>>(tm, memory, n0);
    k_rowdot<<<n1, 256, 0, stream>>>(tm, W0, r1, n0);        // r1 = tanh(mem) @ W0^T
    k_tanh<<<n1 / 256, 256, 0, stream>>>(t1, r1, n1);
    k_bcast_v1_e1<<<(Bn * n1) / 256, 256, 0, stream>>>(v1, e1, e1b, r1, Bn * n1, n1 - 1);
    k_rowdot<<<n2, 256, 0, stream>>>(t1, W1, r2, n1);        // r2 = tanh(r1) @ W1^T
    k_e2_init<<<(Bn * n2) / 256, 256, 0, stream>>>(e2b, batch_inp, r2, Bn * n2, n2 - 1);

    // ---- 8 inference iterations ----
    for (int it = 0; it < 8; ++it) {
        float* loss = out + it;

        // phase 1: G2 (64 tiles) || G1 (32 tiles) — 96 blocks x 512 thr
        GDR g2{e2b, W1Tb, v1, e1, v1, nullptr, T1b, nullptr, lr_ptr, n1, n2, n1 / 64};
        GDR g1{e1b, W0Tb, v0, memory, v0, nullptr, T0b, loss, lr_ptr, n0, n1, n0 / 64};
        pcn_pair<2, 1><<<(n1 / 64) + (n0 / 64), 512, 0, stream>>>(g2, g1, n1 / 64);

        // phase 2: G4 (128 tiles) || G3 (64 tiles) — 192 blocks x 512 thr
        GDR g4{T1b, W1b, batch_inp, nullptr, nullptr, nullptr, e2b, loss, nullptr, n2, n1, n2 / 64};
        GDR g3{T0b, W0b, v1, nullptr, e1, e1b, nullptr, loss, nullptr, n1, n0, n1 / 64};
        pcn_pair<4, 3><<<(n2 / 64) + (n1 / 64), 512, 0, stream>>>(g4, g3, n2 / 64);
    }
}